// Round 9
// baseline (33.962 us; speedup 1.0000x reference)
//
#include <hip/hip_runtime.h>

#define SS 4096
#define OUT_V (8*4096*64)      // 2097152 floats of o, then buckets (262144 floats)
#define ROT_LO_OFS 32768
#define FLAGS_OFS  65536
#define EPS 0.02f

typedef short bf16x8 __attribute__((ext_vector_type(8)));
typedef float f32x4  __attribute__((ext_vector_type(4)));

__device__ __forceinline__ unsigned short f2bf(float x) {
    unsigned int u = __float_as_uint(x);
    u = u + 0x7FFFu + ((u >> 16) & 1u);
    return (unsigned short)(u >> 16);
}

// ---------- pre: rot[64 f][256 d] f32 -> rotT hi/lo bf16 [256 d][64 f] in ws ----------
__global__ __launch_bounds__(256) void lsh_pre(const float* __restrict__ rot,
                                               unsigned short* __restrict__ wh,
                                               unsigned short* __restrict__ wl) {
    const int idx = blockIdx.x * 256 + threadIdx.x;   // 16384
    const int d = idx >> 6, f = idx & 63;
    const float x = rot[f * 256 + d];
    const unsigned short hi = f2bf(x);
    const float hif = __uint_as_float((unsigned int)hi << 16);
    wh[d * 64 + f] = hi;
    wl[d * 64 + f] = f2bf(x - hif);
}

// ---------- main: block = (b, 64-token chunk) x all 256 dirs; 256 thr = 4 waves ----------
// Wave w owns dirs w*64..w*64+63 (hashes 2w, 2w+1). GEMM D[dir][tok] via
// mfma_f32_16x16x32_bf16 with A=rotT (M=dir), B=qk (N=tok), K=64, 3-pass hi/lo split.
// LDS rows are 8 chunks of 8 bf16; chunk' = chunk ^ (row&7) makes frag reads optimal.
__global__ __launch_bounds__(256, 2) void lsh_main(const float* __restrict__ qk,
                                                   const float* __restrict__ v,
                                                   float* __restrict__ out,
                                                   const unsigned short* __restrict__ wh,
                                                   const unsigned short* __restrict__ wl,
                                                   unsigned char* __restrict__ flags) {
    __shared__ __align__(16) unsigned short qh[64 * 64];   // 8 KB
    __shared__ __align__(16) unsigned short ql[64 * 64];   // 8 KB
    __shared__ __align__(16) unsigned short rh[256 * 64];  // 32 KB
    __shared__ __align__(16) unsigned short rl[256 * 64];  // 32 KB

    const int tid = threadIdx.x;
    const int blk = blockIdx.x;        // 512 = 8 b * 64 chunks
    const int b   = blk >> 6;
    const int t0  = (blk & 63) * 64;

    // fused v -> out[0] copy (output 0 == v exactly: self-mask keeps only t==t slots)
    {
        const float4* v4 = (const float4*)v;
        float4*       o4 = (float4*)out;
        const int base = blk * 1024 + tid;
#pragma unroll
        for (int j = 0; j < 4; ++j) o4[base + j * 256] = v4[base + j * 256];
    }

    // stage qk tile [64 tok][64 f] -> bf16 hi/lo, swizzled
    {
        const float4* qg = (const float4*)(qk + (size_t)(b * SS + t0) * 64);
#pragma unroll
        for (int k = 0; k < 4; ++k) {
            const int p = k * 256 + tid;          // 1024 float4
            const int tok = p >> 4, fg = p & 15;
            const float4 x = qg[p];
            const float xs[4] = {x.x, x.y, x.z, x.w};
            unsigned int hp[2], lp[2];
            unsigned short hv[4], lv[4];
#pragma unroll
            for (int e = 0; e < 4; ++e) {
                hv[e] = f2bf(xs[e]);
                lv[e] = f2bf(xs[e] - __uint_as_float((unsigned int)hv[e] << 16));
            }
            hp[0] = hv[0] | ((unsigned int)hv[1] << 16);
            hp[1] = hv[2] | ((unsigned int)hv[3] << 16);
            lp[0] = lv[0] | ((unsigned int)lv[1] << 16);
            lp[1] = lv[2] | ((unsigned int)lv[3] << 16);
            const int chunkp = (fg >> 1) ^ (tok & 7);
            const int ub = tok * 64 + chunkp * 8 + (fg & 1) * 4;
            *(uint2*)&qh[ub] = make_uint2(hp[0], hp[1]);
            *(uint2*)&ql[ub] = make_uint2(lp[0], lp[1]);
        }
    }
    // stage rotT hi/lo [256 d][64 f] from ws, swizzled
    {
        const uint4* rhg = (const uint4*)wh;
        const uint4* rlg = (const uint4*)wl;
#pragma unroll
        for (int k = 0; k < 8; ++k) {
            const int p = k * 256 + tid;          // 2048 chunks
            const int row = p >> 3, c = p & 7;
            const int cp = c ^ (row & 7);
            *(uint4*)&rh[row * 64 + cp * 8] = rhg[p];
            *(uint4*)&rl[row * 64 + cp * 8] = rlg[p];
        }
    }
    __syncthreads();

    const int lane = tid & 63;
    const int w    = tid >> 6;
    const int l15  = lane & 15;
    const int g    = lane >> 4;

    f32x4 acc[4][4];
#pragma unroll
    for (int dt = 0; dt < 4; ++dt)
#pragma unroll
        for (int nt = 0; nt < 4; ++nt) acc[dt][nt] = (f32x4){0.f, 0.f, 0.f, 0.f};

#pragma unroll
    for (int nt = 0; nt < 4; ++nt) {
        const int brow = nt * 16 + l15;
        bf16x8 Bh[2], Bl[2];
#pragma unroll
        for (int ks = 0; ks < 2; ++ks) {
            const int idx = brow * 64 + ((ks * 4 + g) ^ (brow & 7)) * 8;
            Bh[ks] = *(const bf16x8*)&qh[idx];
            Bl[ks] = *(const bf16x8*)&ql[idx];
        }
#pragma unroll
        for (int dt = 0; dt < 4; ++dt) {
            const int arow = (w * 4 + dt) * 16 + l15;
            bf16x8 Ah[2], Al[2];
#pragma unroll
            for (int ks = 0; ks < 2; ++ks) {
                const int idx = arow * 64 + ((ks * 4 + g) ^ (arow & 7)) * 8;
                Ah[ks] = *(const bf16x8*)&rh[idx];
                Al[ks] = *(const bf16x8*)&rl[idx];
            }
            f32x4 c = acc[dt][nt];
#pragma unroll
            for (int ks = 0; ks < 2; ++ks) {
                c = __builtin_amdgcn_mfma_f32_16x16x32_bf16(Al[ks], Bh[ks], c, 0, 0, 0);
                c = __builtin_amdgcn_mfma_f32_16x16x32_bf16(Ah[ks], Bl[ks], c, 0, 0, 0);
                c = __builtin_amdgcn_mfma_f32_16x16x32_bf16(Ah[ks], Bh[ks], c, 0, 0, 0);
            }
            acc[dt][nt] = c;
        }
    }

    // epilogue: per (hash, token-tile) top-2 argmax over concat([r,-r]), flag near-ties.
    // D layout: col = lane&15 (token), row = g*4 + r (dir within 16-tile).
#define UPD(vv, ii) {                                                     \
        if ((vv) > m1)      { m2 = m1; m1 = (vv); i1 = (ii); }            \
        else if ((vv) == m1){ m2 = m1; if ((ii) < i1) i1 = (ii); }        \
        else if ((vv) > m2) { m2 = (vv); }                                \
    }
#pragma unroll
    for (int hh = 0; hh < 2; ++hh) {
        const int h = 2 * w + hh;
#pragma unroll
        for (int nt = 0; nt < 4; ++nt) {
            float m1 = -1e30f, m2 = -1e30f;
            int i1 = 0;
#pragma unroll
            for (int dtl = 0; dtl < 2; ++dtl) {
                const int dt = hh * 2 + dtl;
#pragma unroll
                for (int r = 0; r < 4; ++r) {
                    const float vv = acc[dt][nt][r];
                    const int dl = dtl * 16 + g * 4 + r;
                    UPD(vv, dl);
                    UPD(-vv, 32 + dl);
                }
            }
#pragma unroll
            for (int m = 16; m <= 32; m <<= 1) {
                const float om1 = __shfl_xor(m1, m);
                const int   oi1 = __shfl_xor(i1, m);
                const float om2 = __shfl_xor(m2, m);
                UPD(om1, oi1);
                m2 = fmaxf(m2, om2);
            }
            if (g == 0) {
                const int t = t0 + nt * 16 + l15;
                const int oidx = (b * 8 + h) * SS + t;
                out[OUT_V + oidx] = (float)(i1 + h * 64);
                flags[oidx] = (m1 - m2 < EPS) ? 1 : 0;
            }
        }
    }
#undef UPD
}

// ---------- repair: recompute flagged (b,h,t) pairs exactly in f32 ----------
__global__ __launch_bounds__(256) void lsh_repair(const float* __restrict__ qk,
                                                  const float* __restrict__ rot,
                                                  float* __restrict__ out,
                                                  const unsigned char* __restrict__ flags) {
    const int lane = threadIdx.x & 63;
    const int wid  = (blockIdx.x * 256 + threadIdx.x) >> 6;   // 0..2047
#pragma unroll 1
    for (int gi = 0; gi < 2; ++gi) {
        const int base = wid * 128 + gi * 64;
        unsigned long long mask = __ballot(flags[base + lane] != 0);
        while (mask) {
            const int bit = __ffsll((unsigned long long)mask) - 1;
            mask &= mask - 1;
            const int pair = base + bit;
            const int t  = pair & 4095;
            const int bh = pair >> 12;          // b*8 + h
            const int h  = bh & 7;
            const float* qrow = qk + (size_t)((bh >> 3) * SS + t) * 64;
            const int col = h * 32 + (lane & 31);
            float acc = 0.f;
#pragma unroll
            for (int f = 0; f < 64; ++f)
                acc = fmaf(qrow[f], rot[f * 256 + col], acc);   // same chain order as rounds 1-7
            float val = (lane < 32) ? acc : -acc;
            int   idx = lane;
#pragma unroll
            for (int m = 1; m <= 32; m <<= 1) {
                const float ov = __shfl_xor(val, m);
                const int   oi = __shfl_xor(idx, m);
                if (ov > val || (ov == val && oi < idx)) { val = ov; idx = oi; }
            }
            if (lane == 0) out[OUT_V + pair] = (float)(idx + h * 64);
        }
    }
}

extern "C" void kernel_launch(void* const* d_in, const int* in_sizes, int n_in,
                              void* d_out, int out_size, void* d_ws, size_t ws_size,
                              hipStream_t stream) {
    const float* qk  = (const float*)d_in[0];
    const float* v   = (const float*)d_in[1];
    const float* rot = (const float*)d_in[2];
    float* out = (float*)d_out;
    unsigned short* wh    = (unsigned short*)d_ws;
    unsigned short* wl    = (unsigned short*)((char*)d_ws + ROT_LO_OFS);
    unsigned char*  flags = (unsigned char*)((char*)d_ws + FLAGS_OFS);

    hipLaunchKernelGGL(lsh_pre,    dim3(64),  dim3(256), 0, stream, rot, wh, wl);
    hipLaunchKernelGGL(lsh_main,   dim3(512), dim3(256), 0, stream, qk, v, out, wh, wl, flags);
    hipLaunchKernelGGL(lsh_repair, dim3(512), dim3(256), 0, stream, qk, rot, out, flags);
}